// Round 5
// baseline (232.422 us; speedup 1.0000x reference)
//
#include <hip/hip_runtime.h>
#include <math.h>

#define NN 20000
#define NE 320000
#define NREL 9
#define NBASES 9
#define D_IN 128
#define D_HID 256
#define D_OUT 64
#define LN_EPS 1e-5f

#define N1 (NREL * D_HID + D_HID)   // 2560
#define N2 (NREL * D_OUT + D_OUT)   // 640
#define NBLK ((NN + 255) / 256)     // 79

typedef __attribute__((ext_vector_type(8))) short bf16x8;
typedef __attribute__((ext_vector_type(4))) float f32x4;

__device__ inline ushort f2b(float f) {
    unsigned u = __float_as_uint(f);
    return (ushort)((u + 0x7FFFu + ((u >> 16) & 1u)) >> 16);
}
__device__ inline float b2f(ushort h) { return __uint_as_float(((unsigned)h) << 16); }
__device__ inline unsigned pack2bf(float f0, float f1) {
    return (unsigned)f2b(f0) | ((unsigned)f2b(f1) << 16);
}

// ---------- fused prep: weights (coalesced basis reads) + x cast + dst histogram ----------
__global__ __launch_bounds__(256) void prep_all(
    const float* __restrict__ bases1, const float* __restrict__ comp1, const float* __restrict__ root1,
    const float* __restrict__ bases2, const float* __restrict__ comp2, const float* __restrict__ root2,
    const float* __restrict__ x, const int* __restrict__ dst,
    ushort* __restrict__ w1t, ushort* __restrict__ w2t, ushort* __restrict__ xbf,
    int* __restrict__ deg)
{
    const int SZW1 = D_IN * D_HID;   // 32768
    const int SZW2 = D_HID * D_OUT;  // 16384
    const int SZX  = NN * D_IN;      // 2560000
    int tid = blockIdx.x * 256 + threadIdx.x;
    if (tid < SZW1) {
        int o = tid & (D_HID - 1), k = tid >> 8;          // o lane-minor
        float acc[NREL];
        #pragma unroll
        for (int r = 0; r < NREL; r++) acc[r] = 0.f;
        #pragma unroll
        for (int b = 0; b < NBASES; b++) {
            float bs = bases1[(b * D_IN + k) * D_HID + o];  // coalesced
            #pragma unroll
            for (int r = 0; r < NREL; r++) acc[r] += comp1[r * NBASES + b] * bs;
        }
        #pragma unroll
        for (int r = 0; r < NREL; r++)
            w1t[(r * D_HID + o) * D_IN + k] = f2b(acc[r]);
        w1t[(NREL * D_HID + o) * D_IN + k] = f2b(root1[k * D_HID + o]);  // coalesced read
    } else if (tid < SZW1 + SZW2) {
        int j = tid - SZW1;
        int o = j & (D_OUT - 1), k = j >> 6;
        float acc[NREL];
        #pragma unroll
        for (int r = 0; r < NREL; r++) acc[r] = 0.f;
        #pragma unroll
        for (int b = 0; b < NBASES; b++) {
            float bs = bases2[(b * D_HID + k) * D_OUT + o];  // coalesced
            #pragma unroll
            for (int r = 0; r < NREL; r++) acc[r] += comp2[r * NBASES + b] * bs;
        }
        #pragma unroll
        for (int r = 0; r < NREL; r++)
            w2t[(r * D_OUT + o) * D_HID + k] = f2b(acc[r]);
        w2t[(NREL * D_OUT + o) * D_HID + k] = f2b(root2[k * D_OUT + o]);
    } else if (tid < SZW1 + SZW2 + SZX) {
        int j = tid - SZW1 - SZW2;
        xbf[j] = f2b(x[j]);
    } else if (tid < SZW1 + SZW2 + SZX + NE) {
        int e = tid - SZW1 - SZW2 - SZX;
        atomicAdd(&deg[dst[e]], 1);
    }
}

// ---------- CSR build ----------
__global__ __launch_bounds__(256) void scan_blk(
    const int* __restrict__ deg, int* __restrict__ local, int* __restrict__ bsum)
{
    __shared__ int wsum[4];
    int tid = threadIdx.x, lane = tid & 63, w = tid >> 6;
    int i = blockIdx.x * 256 + tid;
    int v = (i < NN) ? deg[i] : 0;
    int x = v;
    #pragma unroll
    for (int d = 1; d < 64; d <<= 1) {
        int y = __shfl_up(x, d, 64);
        if (lane >= d) x += y;
    }
    if (lane == 63) wsum[w] = x;
    __syncthreads();
    int woff = 0;
    for (int j = 0; j < w; j++) woff += wsum[j];
    if (i < NN) local[i] = woff + x - v;
    if (tid == 255) bsum[blockIdx.x] = woff + x;
}

__global__ __launch_bounds__(256) void scan_fin(
    const int* __restrict__ local, const int* __restrict__ bsum,
    int* __restrict__ offs, int* __restrict__ cursor)
{
    __shared__ int boff_s[NBLK];
    int tid = threadIdx.x;
    if (tid < 64) {
        int carry = 0;
        for (int base = 0; base < NBLK; base += 64) {
            int i = base + tid;
            int v = (i < NBLK) ? bsum[i] : 0;
            int x = v;
            #pragma unroll
            for (int d = 1; d < 64; d <<= 1) {
                int y = __shfl_up(x, d, 64);
                if (tid >= d) x += y;
            }
            if (i < NBLK) boff_s[i] = carry + x - v;
            carry += __shfl(x, 63, 64);
        }
    }
    __syncthreads();
    int i = blockIdx.x * 256 + tid;
    if (i < NN) {
        int o = local[i] + boff_s[i >> 8];
        offs[i] = o;
        cursor[i] = o;
    }
    if (i == NN) offs[NN] = NE;
}

// ep1 = src*N1 + rel*D_HID; ep2 == ep1>>2 exactly, so no ep2 array.
__global__ __launch_bounds__(256) void scatter_ep(
    const int* __restrict__ src, const int* __restrict__ dst, const int* __restrict__ etype,
    int* __restrict__ cursor, int* __restrict__ ep1)
{
    int e = blockIdx.x * 256 + threadIdx.x;
    if (e >= NE) return;
    int d = dst[e];
    int s = src[e], r = etype[e];
    int pos = atomicAdd(&cursor[d], 1);
    ep1[pos] = s * N1 + r * D_HID;
}

// ---------- bf16 MFMA GEMM (BK=128 single-buffer + coalesced epilogue) ----------
// C = A @ Bt^T.  K is tiny (128/256): make the whole K-slab LDS-resident.
// A-tile 128x128 (32KB) + B-tile 128x128 (32KB), single buffer -> per chunk:
// 16x 16B staging loads/thread -> ds_write -> ONE barrier -> 64 MFMAs.
// GEMM1 (K=128): 2 barriers total (was 5).  GEMM2 (K=256): 2 chunks with
// register prefetch of chunk 1 issued under chunk 0's MFMAs.
// LDS slot swizzle = round-0's verified algebra generalized to 16 k-octets
// per 16-row group: slot(r,q) = (r>>4)*256 + q*16 + (((r&15) + 2q)&15).
// Epilogue identical to round 4 (LDS-staged coalesced uint4 stores).
__global__ __launch_bounds__(256) void gemm_bf16(
    const ushort* __restrict__ A, const ushort* __restrict__ Bt, ushort* __restrict__ C,
    int M, int N, int K)
{
    __shared__ ushort smem[32768];  // 64 KB: As[0..16383] | Bs[16384..32767]
    ushort* As = smem;
    ushort* Bs = smem + 16384;

    int tid = threadIdx.x;
    int lane = tid & 63, w = tid >> 6;
    int wm = w >> 1, wn = w & 1;
    int row0 = blockIdx.y * 128, col0 = blockIdx.x * 128;

    // staging: thread covers rows {rr, rr+64} x octets {cc*4 .. cc*4+3}
    int rr = tid >> 2, cc = tid & 3;
    const ushort* gA0 = &A[(size_t)min(row0 + rr, M - 1) * K + cc * 32];
    const ushort* gA1 = &A[(size_t)min(row0 + rr + 64, M - 1) * K + cc * 32];
    const ushort* gB0 = &Bt[(size_t)(col0 + rr) * K + cc * 32];
    const ushort* gB1 = &Bt[(size_t)(col0 + rr + 64) * K + cc * 32];

    int wgo = (rr >> 4) * 256, ri = rr & 15;
    int wofs[4];
    #pragma unroll
    for (int j = 0; j < 4; j++) {
        int q = cc * 4 + j;
        wofs[j] = (wgo + q * 16 + ((ri + 2 * q) & 15)) * 8;  // +8192 for row+64 half
    }

    f32x4 acc[4][4];
    #pragma unroll
    for (int mt = 0; mt < 4; mt++)
        #pragma unroll
        for (int nt = 0; nt < 4; nt++)
            acc[mt][nt] = (f32x4){0.f, 0.f, 0.f, 0.f};

    bf16x8 rA[8], rB[8];
    #pragma unroll
    for (int j = 0; j < 4; j++) {
        rA[j]     = *(const bf16x8*)(gA0 + j * 8);
        rA[4 + j] = *(const bf16x8*)(gA1 + j * 8);
        rB[j]     = *(const bf16x8*)(gB0 + j * 8);
        rB[4 + j] = *(const bf16x8*)(gB1 + j * 8);
    }
    #pragma unroll
    for (int j = 0; j < 4; j++) {
        *(bf16x8*)&As[wofs[j]]        = rA[j];
        *(bf16x8*)&As[wofs[j] + 8192] = rA[4 + j];
        *(bf16x8*)&Bs[wofs[j]]        = rB[j];
        *(bf16x8*)&Bs[wofs[j] + 8192] = rB[4 + j];
    }

    const int NCH = K >> 7;   // 1 for K=128, 2 for K=256
    int mr = lane & 15, kq = lane >> 4;
    for (int kc = 0; kc < NCH; kc++) {
        __syncthreads();
        bool more = (kc + 1 < NCH);
        if (more) {
            int ko = (kc + 1) * 128;
            #pragma unroll
            for (int j = 0; j < 4; j++) {
                rA[j]     = *(const bf16x8*)(gA0 + ko + j * 8);
                rA[4 + j] = *(const bf16x8*)(gA1 + ko + j * 8);
                rB[j]     = *(const bf16x8*)(gB0 + ko + j * 8);
                rB[4 + j] = *(const bf16x8*)(gB1 + ko + j * 8);
            }
        }
        #pragma unroll
        for (int ks = 0; ks < 4; ks++) {
            int q = ks * 4 + kq;
            int ro = (q * 16 + ((mr + 2 * q) & 15)) * 8;
            bf16x8 af[4], bfr[4];
            #pragma unroll
            for (int mt = 0; mt < 4; mt++)
                af[mt] = *(const bf16x8*)&As[(wm * 4 + mt) * 2048 + ro];
            #pragma unroll
            for (int nt = 0; nt < 4; nt++)
                bfr[nt] = *(const bf16x8*)&Bs[(wn * 4 + nt) * 2048 + ro];
            #pragma unroll
            for (int mt = 0; mt < 4; mt++)
                #pragma unroll
                for (int nt = 0; nt < 4; nt++)
                    acc[mt][nt] = __builtin_amdgcn_mfma_f32_16x16x32_bf16(
                        bfr[nt], af[mt], acc[mt][nt], 0, 0, 0);
        }
        if (more) {
            __syncthreads();
            #pragma unroll
            for (int j = 0; j < 4; j++) {
                *(bf16x8*)&As[wofs[j]]        = rA[j];
                *(bf16x8*)&As[wofs[j] + 8192] = rA[4 + j];
                *(bf16x8*)&Bs[wofs[j]]        = rB[j];
                *(bf16x8*)&Bs[wofs[j] + 8192] = rB[4 + j];
            }
        }
    }

    // ---- epilogue: acc -> LDS tile (XOR-swizzled) -> coalesced uint4 stores ----
    __syncthreads();                  // all waves done reading As/Bs
    int qo = lane >> 4, cm = lane & 15;
    #pragma unroll
    for (int mt = 0; mt < 4; mt++) {
        int row = wm * 64 + mt * 16 + cm;
        int sx = (row & 7) << 3;      // XOR in ushort units (16B granularity)
        #pragma unroll
        for (int nt = 0; nt < 4; nt++) {
            int colT = wn * 64 + nt * 16 + qo * 4;
            uint2 o;
            o.x = pack2bf(acc[mt][nt][0], acc[mt][nt][1]);
            o.y = pack2bf(acc[mt][nt][2], acc[mt][nt][3]);
            *(uint2*)&smem[(row * 128 + colT) ^ sx] = o;
        }
    }
    __syncthreads();
    #pragma unroll
    for (int i = 0; i < 8; i++) {
        int rrr = (tid >> 4) + i * 16;
        int seg = tid & 15;
        uint4 val = *(const uint4*)&smem[(rrr * 128 + seg * 8) ^ ((rrr & 7) << 3)];
        int gr = row0 + rrr;
        if (gr < M)
            *(uint4*)&C[(size_t)gr * N + col0 + seg * 8] = val;
    }
}

// ---------- gather1: max over in-edges + root + bias -> LN -> ReLU -> h (bf16) ----------
__global__ __launch_bounds__(256) void gather1(
    const ushort* __restrict__ xw1, const int* __restrict__ offs, const int* __restrict__ ep1,
    const float* __restrict__ bias, const float* __restrict__ g, const float* __restrict__ b,
    ushort* __restrict__ h)
{
    int n = blockIdx.x * 4 + (threadIdx.x >> 6);
    if (n >= NN) return;
    int lane = threadIdx.x & 63;
    int lane4 = lane * 4;
    int e0 = __builtin_amdgcn_readfirstlane(offs[n]);
    int e1 = __builtin_amdgcn_readfirstlane(offs[n + 1]);

    float m0 = -INFINITY, m1 = -INFINITY, m2 = -INFINITY, m3 = -INFINITY;
    int e = e0;
    for (; e + 8 <= e1; e += 8) {
        int p[8];
        #pragma unroll
        for (int j = 0; j < 8; j++) p[j] = ep1[e + j];
        ushort4 v[8];
        #pragma unroll
        for (int j = 0; j < 8; j++) v[j] = *(const ushort4*)&xw1[(size_t)(p[j] + lane4)];
        #pragma unroll
        for (int j = 0; j < 8; j++) {
            m0 = fmaxf(m0, b2f(v[j].x)); m1 = fmaxf(m1, b2f(v[j].y));
            m2 = fmaxf(m2, b2f(v[j].z)); m3 = fmaxf(m3, b2f(v[j].w));
        }
    }
    for (; e + 2 <= e1; e += 2) {
        int pa = ep1[e], pb = ep1[e + 1];
        ushort4 va = *(const ushort4*)&xw1[(size_t)(pa + lane4)];
        ushort4 vb = *(const ushort4*)&xw1[(size_t)(pb + lane4)];
        m0 = fmaxf(m0, fmaxf(b2f(va.x), b2f(vb.x)));
        m1 = fmaxf(m1, fmaxf(b2f(va.y), b2f(vb.y)));
        m2 = fmaxf(m2, fmaxf(b2f(va.z), b2f(vb.z)));
        m3 = fmaxf(m3, fmaxf(b2f(va.w), b2f(vb.w)));
    }
    for (; e < e1; e++) {
        int p = ep1[e];
        ushort4 v = *(const ushort4*)&xw1[(size_t)(p + lane4)];
        m0 = fmaxf(m0, b2f(v.x)); m1 = fmaxf(m1, b2f(v.y));
        m2 = fmaxf(m2, b2f(v.z)); m3 = fmaxf(m3, b2f(v.w));
    }
    if (e1 == e0) { m0 = m1 = m2 = m3 = 0.f; }

    ushort4 rt = *(const ushort4*)&xw1[(size_t)n * N1 + NREL * D_HID + lane4];
    int c = lane4;
    float t0 = m0 + b2f(rt.x) + bias[c + 0];
    float t1 = m1 + b2f(rt.y) + bias[c + 1];
    float t2 = m2 + b2f(rt.z) + bias[c + 2];
    float t3 = m3 + b2f(rt.w) + bias[c + 3];

    float s = t0 + t1 + t2 + t3;
    float s2 = t0 * t0 + t1 * t1 + t2 * t2 + t3 * t3;
    #pragma unroll
    for (int m = 32; m >= 1; m >>= 1) {
        s  += __shfl_xor(s,  m, 64);
        s2 += __shfl_xor(s2, m, 64);
    }
    float mu = s * (1.f / D_HID);
    float var = s2 * (1.f / D_HID) - mu * mu;
    float rs = rsqrtf(var + LN_EPS);

    ushort4 o;
    o.x = f2b(fmaxf((t0 - mu) * rs * g[c + 0] + b[c + 0], 0.f));
    o.y = f2b(fmaxf((t1 - mu) * rs * g[c + 1] + b[c + 1], 0.f));
    o.z = f2b(fmaxf((t2 - mu) * rs * g[c + 2] + b[c + 2], 0.f));
    o.w = f2b(fmaxf((t3 - mu) * rs * g[c + 3] + b[c + 3], 0.f));
    *(ushort4*)&h[(size_t)n * D_HID + c] = o;
}

// ---------- gather2: sum over in-edges + root + bias -> LN -> log_softmax -> out ----------
__global__ __launch_bounds__(256) void gather2(
    const ushort* __restrict__ xw2, const int* __restrict__ offs, const int* __restrict__ ep1,
    const float* __restrict__ bias, const float* __restrict__ g, const float* __restrict__ b,
    float* __restrict__ out)
{
    int n = blockIdx.x * 4 + (threadIdx.x >> 6);
    if (n >= NN) return;
    int lane = threadIdx.x & 63;
    int e0 = __builtin_amdgcn_readfirstlane(offs[n]);
    int e1 = __builtin_amdgcn_readfirstlane(offs[n + 1]);

    float s = 0.f;
    int e = e0;
    for (; e + 8 <= e1; e += 8) {
        int p[8];
        #pragma unroll
        for (int j = 0; j < 8; j++) p[j] = ep1[e + j] >> 2;
        float a[8];
        #pragma unroll
        for (int j = 0; j < 8; j++) a[j] = b2f(xw2[(size_t)(p[j] + lane)]);
        s += ((a[0] + a[1]) + (a[2] + a[3])) + ((a[4] + a[5]) + (a[6] + a[7]));
    }
    for (; e < e1; e++) {
        s += b2f(xw2[(size_t)((ep1[e] >> 2) + lane)]);
    }
    float v = s + b2f(xw2[(size_t)n * N2 + NREL * D_OUT + lane]) + bias[lane];

    float sm = v, s2 = v * v;
    #pragma unroll
    for (int m = 32; m >= 1; m >>= 1) {
        sm += __shfl_xor(sm, m, 64);
        s2 += __shfl_xor(s2, m, 64);
    }
    float mu = sm * (1.f / D_OUT);
    float var = s2 * (1.f / D_OUT) - mu * mu;
    float y = (v - mu) * rsqrtf(var + LN_EPS) * g[lane] + b[lane];

    float mx = y;
    #pragma unroll
    for (int m = 32; m >= 1; m >>= 1) mx = fmaxf(mx, __shfl_xor(mx, m, 64));
    float ex = __expf(y - mx);
    float se = ex;
    #pragma unroll
    for (int m = 32; m >= 1; m >>= 1) se += __shfl_xor(se, m, 64);
    out[(size_t)n * D_OUT + lane] = y - mx - logf(se);
}

extern "C" void kernel_launch(void* const* d_in, const int* in_sizes, int n_in,
                              void* d_out, int out_size, void* d_ws, size_t ws_size,
                              hipStream_t stream)
{
    const float* x      = (const float*)d_in[0];
    const int*   eidx   = (const int*)  d_in[1];
    const int*   etype  = (const int*)  d_in[2];
    const float* bases1 = (const float*)d_in[3];
    const float* comp1  = (const float*)d_in[4];
    const float* root1  = (const float*)d_in[5];
    const float* bias1  = (const float*)d_in[6];
    const float* g1     = (const float*)d_in[7];
    const float* b1     = (const float*)d_in[8];
    const float* bases2 = (const float*)d_in[9];
    const float* comp2  = (const float*)d_in[10];
    const float* root2  = (const float*)d_in[11];
    const float* bias2  = (const float*)d_in[12];
    const float* g2     = (const float*)d_in[13];
    const float* b2     = (const float*)d_in[14];

    const int* src = eidx;
    const int* dst = eidx + NE;

    char* p = (char*)d_ws;
    auto alloc = [&](size_t bytes) -> char* {
        char* r = p;
        p += (bytes + 255) & ~(size_t)255;
        return r;
    };
    ushort* xbf    = (ushort*)alloc((size_t)NN * D_IN * 2);
    ushort* w1t    = (ushort*)alloc((size_t)N1 * D_IN * 2);
    ushort* w2t    = (ushort*)alloc((size_t)N2 * D_HID * 2);
    ushort* xw1    = (ushort*)alloc((size_t)NN * N1 * 2);
    ushort* xw2    = (ushort*)alloc((size_t)NN * N2 * 2);
    ushort* h      = (ushort*)alloc((size_t)NN * D_HID * 2);
    int*    deg    = (int*)   alloc((size_t)NN * 4);
    int*    local  = (int*)   alloc((size_t)NN * 4);
    int*    bsum   = (int*)   alloc((size_t)NBLK * 4);
    int*    offs   = (int*)   alloc((size_t)(NN + 1) * 4);
    int*    cursor = (int*)   alloc((size_t)NN * 4);
    int*    ep1    = (int*)   alloc((size_t)NE * 4);

    hipMemsetAsync(deg, 0, (size_t)NN * 4, stream);
    const int SZP = D_IN * D_HID + D_HID * D_OUT + NN * D_IN + NE;
    prep_all<<<(SZP + 255) / 256, 256, 0, stream>>>(
        bases1, comp1, root1, bases2, comp2, root2, x, dst, w1t, w2t, xbf, deg);

    scan_blk<<<NBLK, 256, 0, stream>>>(deg, local, bsum);
    scan_fin<<<NBLK, 256, 0, stream>>>(local, bsum, offs, cursor);
    scatter_ep<<<(NE + 255) / 256, 256, 0, stream>>>(src, dst, etype, cursor, ep1);

    gemm_bf16<<<dim3(N1 / 128, (NN + 127) / 128), 256, 0, stream>>>(xbf, w1t, xw1, NN, N1, D_IN);
    gather1<<<(NN + 3) / 4, 256, 0, stream>>>(xw1, offs, ep1, bias1, g1, b1, h);

    gemm_bf16<<<dim3(N2 / 128, (NN + 127) / 128), 256, 0, stream>>>(h, w2t, xw2, NN, N2, D_HID);
    gather2<<<(NN + 3) / 4, 256, 0, stream>>>(xw2, offs, ep1, bias2, g2, b2, (float*)d_out);
}

// Round 6
// 225.095 us; speedup vs baseline: 1.0325x; 1.0325x over previous
//
#include <hip/hip_runtime.h>
#include <math.h>

#define NN 20000
#define NE 320000
#define NREL 9
#define NBASES 9
#define D_IN 128
#define D_HID 256
#define D_OUT 64
#define LN_EPS 1e-5f

#define N1 (NREL * D_HID + D_HID)   // 2560
#define N2 (NREL * D_OUT + D_OUT)   // 640
#define NBLK ((NN + 255) / 256)     // 79

typedef __attribute__((ext_vector_type(8))) short bf16x8;
typedef __attribute__((ext_vector_type(4))) float f32x4;

__device__ inline ushort f2b(float f) {
    unsigned u = __float_as_uint(f);
    return (ushort)((u + 0x7FFFu + ((u >> 16) & 1u)) >> 16);
}
__device__ inline float b2f(ushort h) { return __uint_as_float(((unsigned)h) << 16); }
__device__ inline float b2f_lo(unsigned u) { return __uint_as_float(u << 16); }
__device__ inline float b2f_hi(unsigned u) { return __uint_as_float(u & 0xffff0000u); }
__device__ inline unsigned pack2bf(float f0, float f1) {
    return (unsigned)f2b(f0) | ((unsigned)f2b(f1) << 16);
}

// ---------- fused prep: weights (coalesced basis reads) + x cast + dst histogram ----------
__global__ __launch_bounds__(256) void prep_all(
    const float* __restrict__ bases1, const float* __restrict__ comp1, const float* __restrict__ root1,
    const float* __restrict__ bases2, const float* __restrict__ comp2, const float* __restrict__ root2,
    const float* __restrict__ x, const int* __restrict__ dst,
    ushort* __restrict__ w1t, ushort* __restrict__ w2t, ushort* __restrict__ xbf,
    int* __restrict__ deg)
{
    const int SZW1 = D_IN * D_HID;   // 32768
    const int SZW2 = D_HID * D_OUT;  // 16384
    const int SZX  = NN * D_IN;      // 2560000
    int tid = blockIdx.x * 256 + threadIdx.x;
    if (tid < SZW1) {
        int o = tid & (D_HID - 1), k = tid >> 8;          // o lane-minor
        float acc[NREL];
        #pragma unroll
        for (int r = 0; r < NREL; r++) acc[r] = 0.f;
        #pragma unroll
        for (int b = 0; b < NBASES; b++) {
            float bs = bases1[(b * D_IN + k) * D_HID + o];  // coalesced
            #pragma unroll
            for (int r = 0; r < NREL; r++) acc[r] += comp1[r * NBASES + b] * bs;
        }
        #pragma unroll
        for (int r = 0; r < NREL; r++)
            w1t[(r * D_HID + o) * D_IN + k] = f2b(acc[r]);
        w1t[(NREL * D_HID + o) * D_IN + k] = f2b(root1[k * D_HID + o]);  // coalesced read
    } else if (tid < SZW1 + SZW2) {
        int j = tid - SZW1;
        int o = j & (D_OUT - 1), k = j >> 6;
        float acc[NREL];
        #pragma unroll
        for (int r = 0; r < NREL; r++) acc[r] = 0.f;
        #pragma unroll
        for (int b = 0; b < NBASES; b++) {
            float bs = bases2[(b * D_HID + k) * D_OUT + o];  // coalesced
            #pragma unroll
            for (int r = 0; r < NREL; r++) acc[r] += comp2[r * NBASES + b] * bs;
        }
        #pragma unroll
        for (int r = 0; r < NREL; r++)
            w2t[(r * D_OUT + o) * D_HID + k] = f2b(acc[r]);
        w2t[(NREL * D_OUT + o) * D_HID + k] = f2b(root2[k * D_OUT + o]);
    } else if (tid < SZW1 + SZW2 + SZX) {
        int j = tid - SZW1 - SZW2;
        xbf[j] = f2b(x[j]);
    } else if (tid < SZW1 + SZW2 + SZX + NE) {
        int e = tid - SZW1 - SZW2 - SZX;
        atomicAdd(&deg[dst[e]], 1);
    }
}

// ---------- CSR build ----------
__global__ __launch_bounds__(256) void scan_blk(
    const int* __restrict__ deg, int* __restrict__ local, int* __restrict__ bsum)
{
    __shared__ int wsum[4];
    int tid = threadIdx.x, lane = tid & 63, w = tid >> 6;
    int i = blockIdx.x * 256 + tid;
    int v = (i < NN) ? deg[i] : 0;
    int x = v;
    #pragma unroll
    for (int d = 1; d < 64; d <<= 1) {
        int y = __shfl_up(x, d, 64);
        if (lane >= d) x += y;
    }
    if (lane == 63) wsum[w] = x;
    __syncthreads();
    int woff = 0;
    for (int j = 0; j < w; j++) woff += wsum[j];
    if (i < NN) local[i] = woff + x - v;
    if (tid == 255) bsum[blockIdx.x] = woff + x;
}

__global__ __launch_bounds__(256) void scan_fin(
    const int* __restrict__ local, const int* __restrict__ bsum,
    int* __restrict__ offs, int* __restrict__ cursor)
{
    __shared__ int boff_s[NBLK];
    int tid = threadIdx.x;
    if (tid < 64) {
        int carry = 0;
        for (int base = 0; base < NBLK; base += 64) {
            int i = base + tid;
            int v = (i < NBLK) ? bsum[i] : 0;
            int x = v;
            #pragma unroll
            for (int d = 1; d < 64; d <<= 1) {
                int y = __shfl_up(x, d, 64);
                if (tid >= d) x += y;
            }
            if (i < NBLK) boff_s[i] = carry + x - v;
            carry += __shfl(x, 63, 64);
        }
    }
    __syncthreads();
    int i = blockIdx.x * 256 + tid;
    if (i < NN) {
        int o = local[i] + boff_s[i >> 8];
        offs[i] = o;
        cursor[i] = o;
    }
    if (i == NN) offs[NN] = NE;
}

// ep1 = src*N1 + rel*D_HID; ep2 == ep1>>2 exactly, so no ep2 array.
__global__ __launch_bounds__(256) void scatter_ep(
    const int* __restrict__ src, const int* __restrict__ dst, const int* __restrict__ etype,
    int* __restrict__ cursor, int* __restrict__ ep1)
{
    int e = blockIdx.x * 256 + threadIdx.x;
    if (e >= NE) return;
    int d = dst[e];
    int s = src[e], r = etype[e];
    int pos = atomicAdd(&cursor[d], 1);
    ep1[pos] = s * N1 + r * D_HID;
}

// ---------- bf16 MFMA GEMM (round-4 proven config): C = A @ Bt^T ----------
// 128x128 tile, BK=32, double-buffered LDS, VGPR reg-staging, swizzled LDS
// slots, operand-swapped MFMA; epilogue stages C-tile in LDS (XOR-swizzled)
// and stores fully-coalesced uint4 (the round-4 win: 48 -> <41 us).
__global__ __launch_bounds__(256) void gemm_bf16(
    const ushort* __restrict__ A, const ushort* __restrict__ Bt, ushort* __restrict__ C,
    int M, int N, int K)
{
    __shared__ ushort smem[16384];  // As[2][4096] | Bs[2][4096]; epilogue reuses all 32KB

    ushort* Asb = smem;             // As[buf] = Asb + buf*4096
    ushort* Bsb = smem + 8192;      // Bs[buf] = Bsb + buf*4096

    int tid = threadIdx.x;
    int lane = tid & 63, w = tid >> 6;
    int wm = w >> 1, wn = w & 1;
    int row0 = blockIdx.y * 128, col0 = blockIdx.x * 128;

    int r0 = tid >> 2, q0 = tid & 3;
    int mrw = r0 & 15, gw = r0 >> 4;
    int sw = q0 * 16 + ((mrw + 2 * q0) & 15);
    int lo0 = (gw * 64 + sw) * 8;
    int lo1 = ((gw + 4) * 64 + sw) * 8;
    int arow0 = min(row0 + r0, M - 1);
    int arow1 = min(row0 + r0 + 64, M - 1);
    const ushort* gA0 = &A[(size_t)arow0 * K + q0 * 8];
    const ushort* gA1 = &A[(size_t)arow1 * K + q0 * 8];
    const ushort* gB0 = &Bt[(size_t)(col0 + r0) * K + q0 * 8];
    const ushort* gB1 = &Bt[(size_t)(col0 + r0 + 64) * K + q0 * 8];

    int mr = lane & 15, kq = lane >> 4;
    int inner = (kq * 16 + ((mr + 2 * kq) & 15)) * 8;

    f32x4 acc[4][4];
    #pragma unroll
    for (int mt = 0; mt < 4; mt++)
        #pragma unroll
        for (int nt = 0; nt < 4; nt++)
            acc[mt][nt] = (f32x4){0.f, 0.f, 0.f, 0.f};

    {
        bf16x8 a0 = *(const bf16x8*)gA0;
        bf16x8 a1 = *(const bf16x8*)gA1;
        bf16x8 b0 = *(const bf16x8*)gB0;
        bf16x8 b1 = *(const bf16x8*)gB1;
        *(bf16x8*)&Asb[lo0] = a0;
        *(bf16x8*)&Asb[lo1] = a1;
        *(bf16x8*)&Bsb[lo0] = b0;
        *(bf16x8*)&Bsb[lo1] = b1;
    }

    const int NC = K >> 5;
    for (int c = 0; c < NC; c++) {
        __syncthreads();
        int cur = c & 1, nxt = cur ^ 1;
        bf16x8 a0, a1, b0, b1;
        bool more = (c + 1 < NC);
        if (more) {
            gA0 += 32; gA1 += 32; gB0 += 32; gB1 += 32;
            a0 = *(const bf16x8*)gA0;
            a1 = *(const bf16x8*)gA1;
            b0 = *(const bf16x8*)gB0;
            b1 = *(const bf16x8*)gB1;
        }

        bf16x8 af[4], bfr[4];
        #pragma unroll
        for (int mt = 0; mt < 4; mt++)
            af[mt] = *(const bf16x8*)&Asb[cur * 4096 + ((wm * 4 + mt) * 64) * 8 + inner];
        #pragma unroll
        for (int nt = 0; nt < 4; nt++)
            bfr[nt] = *(const bf16x8*)&Bsb[cur * 4096 + ((wn * 4 + nt) * 64) * 8 + inner];
        #pragma unroll
        for (int mt = 0; mt < 4; mt++)
            #pragma unroll
            for (int nt = 0; nt < 4; nt++)
                acc[mt][nt] = __builtin_amdgcn_mfma_f32_16x16x32_bf16(
                    bfr[nt], af[mt], acc[mt][nt], 0, 0, 0);

        if (more) {
            *(bf16x8*)&Asb[nxt * 4096 + lo0] = a0;
            *(bf16x8*)&Asb[nxt * 4096 + lo1] = a1;
            *(bf16x8*)&Bsb[nxt * 4096 + lo0] = b0;
            *(bf16x8*)&Bsb[nxt * 4096 + lo1] = b1;
        }
    }

    // ---- epilogue: acc -> LDS tile (XOR-swizzled) -> coalesced uint4 stores ----
    __syncthreads();                  // all waves done reading As/Bs
    int qo = lane >> 4, cm = lane & 15;
    #pragma unroll
    for (int mt = 0; mt < 4; mt++) {
        int row = wm * 64 + mt * 16 + cm;
        int sx = (row & 7) << 3;      // XOR in ushort units (16B granularity)
        #pragma unroll
        for (int nt = 0; nt < 4; nt++) {
            int colT = wn * 64 + nt * 16 + qo * 4;
            uint2 o;
            o.x = pack2bf(acc[mt][nt][0], acc[mt][nt][1]);
            o.y = pack2bf(acc[mt][nt][2], acc[mt][nt][3]);
            *(uint2*)&smem[(row * 128 + colT) ^ sx] = o;
        }
    }
    __syncthreads();
    #pragma unroll
    for (int i = 0; i < 8; i++) {
        int rr = (tid >> 4) + i * 16;
        int seg = tid & 15;
        uint4 val = *(const uint4*)&smem[(rr * 128 + seg * 8) ^ ((rr & 7) << 3)];
        int gr = row0 + rr;
        if (gr < M)
            *(uint4*)&C[(size_t)gr * N + col0 + seg * 8] = val;
    }
}

// ---------- gather1: max over in-edges + root + bias -> LN -> ReLU -> h (bf16) ----------
// v6: half-wave edge parallelism. Lanes 0-31 take even edges, 32-63 odd;
// each lane loads uint4 (16B, 8 cols) -> load instructions per edge 64x8B ->
// 32x16B. Parity halves merged with one shfl_xor(32) per col (max is
// idempotent -> odd-tail duplication across halves is safe). Each lane then
// owns 4 disjoint cols (8*il + 4*hf + k); LN reduction unchanged.
__global__ __launch_bounds__(256) void gather1(
    const ushort* __restrict__ xw1, const int* __restrict__ offs, const int* __restrict__ ep1,
    const float* __restrict__ bias, const float* __restrict__ g, const float* __restrict__ b,
    ushort* __restrict__ hout)
{
    int n = blockIdx.x * 4 + (threadIdx.x >> 6);
    if (n >= NN) return;
    int lane = threadIdx.x & 63;
    int hf = lane >> 5;               // edge parity handled by this half
    int il = lane & 31;               // col octet 8*il .. 8*il+7
    int cbase = il * 8;
    int e0 = __builtin_amdgcn_readfirstlane(offs[n]);
    int e1 = __builtin_amdgcn_readfirstlane(offs[n + 1]);

    float m[8];
    #pragma unroll
    for (int k = 0; k < 8; k++) m[k] = -INFINITY;

    int e = e0;
    for (; e + 8 <= e1; e += 8) {       // 8 edges: this half takes 4
        int p[4];
        #pragma unroll
        for (int j = 0; j < 4; j++) p[j] = ep1[e + 2 * j + hf];
        uint4 v[4];
        #pragma unroll
        for (int j = 0; j < 4; j++) v[j] = *(const uint4*)&xw1[(size_t)p[j] + cbase];
        #pragma unroll
        for (int j = 0; j < 4; j++) {
            m[0] = fmaxf(m[0], b2f_lo(v[j].x)); m[1] = fmaxf(m[1], b2f_hi(v[j].x));
            m[2] = fmaxf(m[2], b2f_lo(v[j].y)); m[3] = fmaxf(m[3], b2f_hi(v[j].y));
            m[4] = fmaxf(m[4], b2f_lo(v[j].z)); m[5] = fmaxf(m[5], b2f_hi(v[j].z));
            m[6] = fmaxf(m[6], b2f_lo(v[j].w)); m[7] = fmaxf(m[7], b2f_hi(v[j].w));
        }
    }
    for (; e < e1; e += 2) {            // tail: duplicate last edge for odd count (max-safe)
        int ee = min(e + hf, e1 - 1);
        int p = ep1[ee];
        uint4 v = *(const uint4*)&xw1[(size_t)p + cbase];
        m[0] = fmaxf(m[0], b2f_lo(v.x)); m[1] = fmaxf(m[1], b2f_hi(v.x));
        m[2] = fmaxf(m[2], b2f_lo(v.y)); m[3] = fmaxf(m[3], b2f_hi(v.y));
        m[4] = fmaxf(m[4], b2f_lo(v.z)); m[5] = fmaxf(m[5], b2f_hi(v.z));
        m[6] = fmaxf(m[6], b2f_lo(v.w)); m[7] = fmaxf(m[7], b2f_hi(v.w));
    }
    #pragma unroll
    for (int k = 0; k < 8; k++) m[k] = fmaxf(m[k], __shfl_xor(m[k], 32, 64));
    if (e1 == e0) {
        #pragma unroll
        for (int k = 0; k < 8; k++) m[k] = 0.f;
    }

    // this lane finalizes cols c0..c0+3 (compile-time indices only; rule #20)
    int c0 = cbase + hf * 4;
    float a0 = hf ? m[4] : m[0];
    float a1 = hf ? m[5] : m[1];
    float a2 = hf ? m[6] : m[2];
    float a3 = hf ? m[7] : m[3];

    ushort4 rt = *(const ushort4*)&xw1[(size_t)n * N1 + NREL * D_HID + c0];
    float t0 = a0 + b2f(rt.x) + bias[c0 + 0];
    float t1 = a1 + b2f(rt.y) + bias[c0 + 1];
    float t2 = a2 + b2f(rt.z) + bias[c0 + 2];
    float t3 = a3 + b2f(rt.w) + bias[c0 + 3];

    float s = t0 + t1 + t2 + t3;
    float s2 = t0 * t0 + t1 * t1 + t2 * t2 + t3 * t3;
    #pragma unroll
    for (int mm = 32; mm >= 1; mm >>= 1) {
        s  += __shfl_xor(s,  mm, 64);
        s2 += __shfl_xor(s2, mm, 64);
    }
    float mu = s * (1.f / D_HID);
    float var = s2 * (1.f / D_HID) - mu * mu;
    float rs = rsqrtf(var + LN_EPS);

    ushort4 o;
    o.x = f2b(fmaxf((t0 - mu) * rs * g[c0 + 0] + b[c0 + 0], 0.f));
    o.y = f2b(fmaxf((t1 - mu) * rs * g[c0 + 1] + b[c0 + 1], 0.f));
    o.z = f2b(fmaxf((t2 - mu) * rs * g[c0 + 2] + b[c0 + 2], 0.f));
    o.w = f2b(fmaxf((t3 - mu) * rs * g[c0 + 3] + b[c0 + 3], 0.f));
    *(ushort4*)&hout[(size_t)n * D_HID + c0] = o;
}

// ---------- gather2: sum over in-edges + root + bias -> LN -> log_softmax -> out ----------
// v6: quarter-wave edge parallelism. 16 lanes x uint2 (8B, 4 cols) cover the
// 64-col row; 4 edge slots in flight (was 64 x 2B scalar loads per edge).
// Slot partial sums merged via shfl_xor(16,32); lane then owns col 4*ql+q
// (bijective). Tail is guarded (sum is not idempotent).
__global__ __launch_bounds__(256) void gather2(
    const ushort* __restrict__ xw2, const int* __restrict__ offs, const int* __restrict__ ep1,
    const float* __restrict__ bias, const float* __restrict__ g, const float* __restrict__ b,
    float* __restrict__ out)
{
    int n = blockIdx.x * 4 + (threadIdx.x >> 6);
    if (n >= NN) return;
    int lane = threadIdx.x & 63;
    int q = lane >> 4;                // edge slot 0..3
    int ql = lane & 15;               // col quad 4*ql .. 4*ql+3
    int cb = ql * 4;
    int e0 = __builtin_amdgcn_readfirstlane(offs[n]);
    int e1 = __builtin_amdgcn_readfirstlane(offs[n + 1]);

    float s0 = 0.f, s1 = 0.f, s2p = 0.f, s3 = 0.f;
    int e = e0;
    for (; e + 8 <= e1; e += 8) {     // 8 edges: this slot takes e+q, e+4+q
        int pa = ep1[e + q] >> 2;
        int pb = ep1[e + 4 + q] >> 2;
        uint2 va = *(const uint2*)&xw2[(size_t)pa + cb];
        uint2 vb = *(const uint2*)&xw2[(size_t)pb + cb];
        s0 += b2f_lo(va.x) + b2f_lo(vb.x);
        s1 += b2f_hi(va.x) + b2f_hi(vb.x);
        s2p += b2f_lo(va.y) + b2f_lo(vb.y);
        s3 += b2f_hi(va.y) + b2f_hi(vb.y);
    }
    for (; e < e1; e += 4) {
        if (e + q < e1) {
            int p = ep1[e + q] >> 2;
            uint2 v = *(const uint2*)&xw2[(size_t)p + cb];
            s0 += b2f_lo(v.x); s1 += b2f_hi(v.x);
            s2p += b2f_lo(v.y); s3 += b2f_hi(v.y);
        }
    }
    // merge the 4 edge slots (replicas at ql, ql+16, ql+32, ql+48)
    s0 += __shfl_xor(s0, 16, 64); s0 += __shfl_xor(s0, 32, 64);
    s1 += __shfl_xor(s1, 16, 64); s1 += __shfl_xor(s1, 32, 64);
    s2p += __shfl_xor(s2p, 16, 64); s2p += __shfl_xor(s2p, 32, 64);
    s3 += __shfl_xor(s3, 16, 64); s3 += __shfl_xor(s3, 32, 64);

    int c = cb + q;                   // this lane's output column (bijective)
    float agg = (q == 0) ? s0 : (q == 1) ? s1 : (q == 2) ? s2p : s3;
    float v = agg + b2f(xw2[(size_t)n * N2 + NREL * D_OUT + c]) + bias[c];

    float sm = v, sq = v * v;
    #pragma unroll
    for (int mm = 32; mm >= 1; mm >>= 1) {
        sm += __shfl_xor(sm, mm, 64);
        sq += __shfl_xor(sq, mm, 64);
    }
    float mu = sm * (1.f / D_OUT);
    float var = sq * (1.f / D_OUT) - mu * mu;
    float y = (v - mu) * rsqrtf(var + LN_EPS) * g[c] + b[c];

    float mx = y;
    #pragma unroll
    for (int mm = 32; mm >= 1; mm >>= 1) mx = fmaxf(mx, __shfl_xor(mx, mm, 64));
    float ex = __expf(y - mx);
    float se = ex;
    #pragma unroll
    for (int mm = 32; mm >= 1; mm >>= 1) se += __shfl_xor(se, mm, 64);
    out[(size_t)n * D_OUT + c] = y - mx - logf(se);
}

extern "C" void kernel_launch(void* const* d_in, const int* in_sizes, int n_in,
                              void* d_out, int out_size, void* d_ws, size_t ws_size,
                              hipStream_t stream)
{
    const float* x      = (const float*)d_in[0];
    const int*   eidx   = (const int*)  d_in[1];
    const int*   etype  = (const int*)  d_in[2];
    const float* bases1 = (const float*)d_in[3];
    const float* comp1  = (const float*)d_in[4];
    const float* root1  = (const float*)d_in[5];
    const float* bias1  = (const float*)d_in[6];
    const float* g1     = (const float*)d_in[7];
    const float* b1     = (const float*)d_in[8];
    const float* bases2 = (const float*)d_in[9];
    const float* comp2  = (const float*)d_in[10];
    const float* root2  = (const float*)d_in[11];
    const float* bias2  = (const float*)d_in[12];
    const float* g2     = (const float*)d_in[13];
    const float* b2     = (const float*)d_in[14];

    const int* src = eidx;
    const int* dst = eidx + NE;

    char* p = (char*)d_ws;
    auto alloc = [&](size_t bytes) -> char* {
        char* r = p;
        p += (bytes + 255) & ~(size_t)255;
        return r;
    };
    ushort* xbf    = (ushort*)alloc((size_t)NN * D_IN * 2);
    ushort* w1t    = (ushort*)alloc((size_t)N1 * D_IN * 2);
    ushort* w2t    = (ushort*)alloc((size_t)N2 * D_HID * 2);
    ushort* xw1    = (ushort*)alloc((size_t)NN * N1 * 2);
    ushort* xw2    = (ushort*)alloc((size_t)NN * N2 * 2);
    ushort* h      = (ushort*)alloc((size_t)NN * D_HID * 2);
    int*    deg    = (int*)   alloc((size_t)NN * 4);
    int*    local  = (int*)   alloc((size_t)NN * 4);
    int*    bsum   = (int*)   alloc((size_t)NBLK * 4);
    int*    offs   = (int*)   alloc((size_t)(NN + 1) * 4);
    int*    cursor = (int*)   alloc((size_t)NN * 4);
    int*    ep1    = (int*)   alloc((size_t)NE * 4);

    hipMemsetAsync(deg, 0, (size_t)NN * 4, stream);
    const int SZP = D_IN * D_HID + D_HID * D_OUT + NN * D_IN + NE;
    prep_all<<<(SZP + 255) / 256, 256, 0, stream>>>(
        bases1, comp1, root1, bases2, comp2, root2, x, dst, w1t, w2t, xbf, deg);

    scan_blk<<<NBLK, 256, 0, stream>>>(deg, local, bsum);
    scan_fin<<<NBLK, 256, 0, stream>>>(local, bsum, offs, cursor);
    scatter_ep<<<(NE + 255) / 256, 256, 0, stream>>>(src, dst, etype, cursor, ep1);

    gemm_bf16<<<dim3(N1 / 128, (NN + 127) / 128), 256, 0, stream>>>(xbf, w1t, xw1, NN, N1, D_IN);
    gather1<<<(NN + 3) / 4, 256, 0, stream>>>(xw1, offs, ep1, bias1, g1, b1, h);

    gemm_bf16<<<dim3(N2 / 128, (NN + 127) / 128), 256, 0, stream>>>(h, w2t, xw2, NN, N2, D_HID);
    gather2<<<(NN + 3) / 4, 256, 0, stream>>>(xw2, offs, ep1, bias2, g2, b2, (float*)d_out);
}

// Round 7
// 219.697 us; speedup vs baseline: 1.0579x; 1.0246x over previous
//
#include <hip/hip_runtime.h>
#include <math.h>

#define NN 20000
#define NE 320000
#define NREL 9
#define NBASES 9
#define D_IN 128
#define D_HID 256
#define D_OUT 64
#define LN_EPS 1e-5f

#define N1 (NREL * D_HID + D_HID)   // 2560
#define N2 (NREL * D_OUT + D_OUT)   // 640
#define NBLK ((NN + 255) / 256)     // 79

typedef __attribute__((ext_vector_type(8))) short bf16x8;
typedef __attribute__((ext_vector_type(4))) float f32x4;

__device__ inline ushort f2b(float f) {
    unsigned u = __float_as_uint(f);
    return (ushort)((u + 0x7FFFu + ((u >> 16) & 1u)) >> 16);
}
__device__ inline float b2f(ushort h) { return __uint_as_float(((unsigned)h) << 16); }
__device__ inline float b2f_lo(unsigned u) { return __uint_as_float(u << 16); }
__device__ inline float b2f_hi(unsigned u) { return __uint_as_float(u & 0xffff0000u); }
__device__ inline unsigned pack2bf(float f0, float f1) {
    return (unsigned)f2b(f0) | ((unsigned)f2b(f1) << 16);
}

// ---------- fused prep: weights (coalesced basis reads) + x cast + dst histogram ----------
__global__ __launch_bounds__(256) void prep_all(
    const float* __restrict__ bases1, const float* __restrict__ comp1, const float* __restrict__ root1,
    const float* __restrict__ bases2, const float* __restrict__ comp2, const float* __restrict__ root2,
    const float* __restrict__ x, const int* __restrict__ dst,
    ushort* __restrict__ w1t, ushort* __restrict__ w2t, ushort* __restrict__ xbf,
    int* __restrict__ deg)
{
    const int SZW1 = D_IN * D_HID;   // 32768
    const int SZW2 = D_HID * D_OUT;  // 16384
    const int SZX  = NN * D_IN;      // 2560000
    int tid = blockIdx.x * 256 + threadIdx.x;
    if (tid < SZW1) {
        int o = tid & (D_HID - 1), k = tid >> 8;          // o lane-minor
        float acc[NREL];
        #pragma unroll
        for (int r = 0; r < NREL; r++) acc[r] = 0.f;
        #pragma unroll
        for (int b = 0; b < NBASES; b++) {
            float bs = bases1[(b * D_IN + k) * D_HID + o];  // coalesced
            #pragma unroll
            for (int r = 0; r < NREL; r++) acc[r] += comp1[r * NBASES + b] * bs;
        }
        #pragma unroll
        for (int r = 0; r < NREL; r++)
            w1t[(r * D_HID + o) * D_IN + k] = f2b(acc[r]);
        w1t[(NREL * D_HID + o) * D_IN + k] = f2b(root1[k * D_HID + o]);  // coalesced read
    } else if (tid < SZW1 + SZW2) {
        int j = tid - SZW1;
        int o = j & (D_OUT - 1), k = j >> 6;
        float acc[NREL];
        #pragma unroll
        for (int r = 0; r < NREL; r++) acc[r] = 0.f;
        #pragma unroll
        for (int b = 0; b < NBASES; b++) {
            float bs = bases2[(b * D_HID + k) * D_OUT + o];  // coalesced
            #pragma unroll
            for (int r = 0; r < NREL; r++) acc[r] += comp2[r * NBASES + b] * bs;
        }
        #pragma unroll
        for (int r = 0; r < NREL; r++)
            w2t[(r * D_OUT + o) * D_HID + k] = f2b(acc[r]);
        w2t[(NREL * D_OUT + o) * D_HID + k] = f2b(root2[k * D_OUT + o]);
    } else if (tid < SZW1 + SZW2 + SZX) {
        int j = tid - SZW1 - SZW2;
        xbf[j] = f2b(x[j]);
    } else if (tid < SZW1 + SZW2 + SZX + NE) {
        int e = tid - SZW1 - SZW2 - SZX;
        atomicAdd(&deg[dst[e]], 1);
    }
}

// ---------- CSR build ----------
__global__ __launch_bounds__(256) void scan_blk(
    const int* __restrict__ deg, int* __restrict__ local, int* __restrict__ bsum)
{
    __shared__ int wsum[4];
    int tid = threadIdx.x, lane = tid & 63, w = tid >> 6;
    int i = blockIdx.x * 256 + tid;
    int v = (i < NN) ? deg[i] : 0;
    int x = v;
    #pragma unroll
    for (int d = 1; d < 64; d <<= 1) {
        int y = __shfl_up(x, d, 64);
        if (lane >= d) x += y;
    }
    if (lane == 63) wsum[w] = x;
    __syncthreads();
    int woff = 0;
    for (int j = 0; j < w; j++) woff += wsum[j];
    if (i < NN) local[i] = woff + x - v;
    if (tid == 255) bsum[blockIdx.x] = woff + x;
}

__global__ __launch_bounds__(256) void scan_fin(
    const int* __restrict__ local, const int* __restrict__ bsum,
    int* __restrict__ offs, int* __restrict__ cursor)
{
    __shared__ int boff_s[NBLK];
    int tid = threadIdx.x;
    if (tid < 64) {
        int carry = 0;
        for (int base = 0; base < NBLK; base += 64) {
            int i = base + tid;
            int v = (i < NBLK) ? bsum[i] : 0;
            int x = v;
            #pragma unroll
            for (int d = 1; d < 64; d <<= 1) {
                int y = __shfl_up(x, d, 64);
                if (tid >= d) x += y;
            }
            if (i < NBLK) boff_s[i] = carry + x - v;
            carry += __shfl(x, 63, 64);
        }
    }
    __syncthreads();
    int i = blockIdx.x * 256 + tid;
    if (i < NN) {
        int o = local[i] + boff_s[i >> 8];
        offs[i] = o;
        cursor[i] = o;
    }
    if (i == NN) offs[NN] = NE;
}

// ep1 = src*N1 + rel*D_HID; ep2 == ep1>>2 exactly, so no ep2 array.
__global__ __launch_bounds__(256) void scatter_ep(
    const int* __restrict__ src, const int* __restrict__ dst, const int* __restrict__ etype,
    int* __restrict__ cursor, int* __restrict__ ep1)
{
    int e = blockIdx.x * 256 + threadIdx.x;
    if (e >= NE) return;
    int d = dst[e];
    int s = src[e], r = etype[e];
    int pos = atomicAdd(&cursor[d], 1);
    ep1[pos] = s * N1 + r * D_HID;
}

// ---------- bf16 MFMA GEMM (8-wave occupancy variant of the round-4 kernel) ----------
// C = A @ Bt^T.  Identical 128x128 tile, BK=32 double-buffered LDS, VGPR
// reg-staging, swizzled LDS slots, operand-swapped MFMA, and the round-4
// coalesced LDS-staged epilogue.  ONLY the wave decomposition changes:
// 512 threads / 8 waves, wave-tile 32x64 -> acc[2][4] = 32 AGPRs per wave
// (was 64), staging 1 A-slot + 1 B-slot (16B) per thread.  Register budget
// ~90/wave -> 4-6 waves/SIMD resident (was ~2) so staging stalls of some
// waves interleave with MFMA/epilogue phases of others.
__global__ __launch_bounds__(512) void gemm_bf16(
    const ushort* __restrict__ A, const ushort* __restrict__ Bt, ushort* __restrict__ C,
    int M, int N, int K)
{
    __shared__ ushort smem[16384];  // As[2][4096] | Bs[2][4096]; epilogue reuses all 32KB
    ushort* Asb = smem;
    ushort* Bsb = smem + 8192;

    int tid = threadIdx.x;
    int lane = tid & 63, w = tid >> 6;        // 8 waves
    int wm = w >> 1, wn = w & 1;              // wm 0..3 (row), wn 0..1 (col)
    int row0 = blockIdx.y * 128, col0 = blockIdx.x * 128;

    // staging: thread stages A slot tid and B slot tid (16B each per chunk)
    int r0 = tid >> 2, q0 = tid & 3;          // r0 0..127, q0 = k-quarter
    int mrw = r0 & 15, gw = r0 >> 4;
    int sw = q0 * 16 + ((mrw + 2 * q0) & 15);
    int lo = (gw * 64 + sw) * 8;
    int arow = min(row0 + r0, M - 1);
    const ushort* gA = &A[(size_t)arow * K + q0 * 8];
    const ushort* gB = &Bt[(size_t)(col0 + r0) * K + q0 * 8];

    int mr = lane & 15, kq = lane >> 4;
    int inner = (kq * 16 + ((mr + 2 * kq) & 15)) * 8;

    f32x4 acc[2][4];
    #pragma unroll
    for (int mt = 0; mt < 2; mt++)
        #pragma unroll
        for (int nt = 0; nt < 4; nt++)
            acc[mt][nt] = (f32x4){0.f, 0.f, 0.f, 0.f};

    {
        bf16x8 a0 = *(const bf16x8*)gA;
        bf16x8 b0 = *(const bf16x8*)gB;
        *(bf16x8*)&Asb[lo] = a0;
        *(bf16x8*)&Bsb[lo] = b0;
    }

    const int NC = K >> 5;
    for (int c = 0; c < NC; c++) {
        __syncthreads();
        int cur = c & 1, nxt = cur ^ 1;
        bf16x8 a0, b0;
        bool more = (c + 1 < NC);
        if (more) {
            gA += 32; gB += 32;
            a0 = *(const bf16x8*)gA;
            b0 = *(const bf16x8*)gB;
        }

        bf16x8 af[2], bfr[4];
        #pragma unroll
        for (int mt = 0; mt < 2; mt++)
            af[mt] = *(const bf16x8*)&Asb[cur * 4096 + ((wm * 2 + mt) * 64) * 8 + inner];
        #pragma unroll
        for (int nt = 0; nt < 4; nt++)
            bfr[nt] = *(const bf16x8*)&Bsb[cur * 4096 + ((wn * 4 + nt) * 64) * 8 + inner];
        #pragma unroll
        for (int mt = 0; mt < 2; mt++)
            #pragma unroll
            for (int nt = 0; nt < 4; nt++)
                acc[mt][nt] = __builtin_amdgcn_mfma_f32_16x16x32_bf16(
                    bfr[nt], af[mt], acc[mt][nt], 0, 0, 0);

        if (more) {
            *(bf16x8*)&Asb[nxt * 4096 + lo] = a0;
            *(bf16x8*)&Bsb[nxt * 4096 + lo] = b0;
        }
    }

    // ---- epilogue: acc -> LDS tile (XOR-swizzled) -> coalesced uint4 stores ----
    __syncthreads();                  // all waves done reading As/Bs
    int qo = lane >> 4, cm = lane & 15;
    #pragma unroll
    for (int mt = 0; mt < 2; mt++) {
        int row = wm * 32 + mt * 16 + cm;
        int sx = (row & 7) << 3;      // XOR in ushort units (16B granularity)
        #pragma unroll
        for (int nt = 0; nt < 4; nt++) {
            int colT = wn * 64 + nt * 16 + qo * 4;
            uint2 o;
            o.x = pack2bf(acc[mt][nt][0], acc[mt][nt][1]);
            o.y = pack2bf(acc[mt][nt][2], acc[mt][nt][3]);
            *(uint2*)&smem[(row * 128 + colT) ^ sx] = o;
        }
    }
    __syncthreads();
    #pragma unroll
    for (int i = 0; i < 4; i++) {
        int rr = (tid >> 4) + i * 32;     // tid>>4 in 0..31
        int seg = tid & 15;
        uint4 val = *(const uint4*)&smem[(rr * 128 + seg * 8) ^ ((rr & 7) << 3)];
        int gr = row0 + rr;
        if (gr < M)
            *(uint4*)&C[(size_t)gr * N + col0 + seg * 8] = val;
    }
}

// ---------- gather1: max over in-edges + root + bias -> LN -> ReLU -> h (bf16) ----------
// half-wave edge parallelism; each lane loads uint4 (8 cols); parity halves
// merged via shfl_xor(32) (max idempotent -> odd-tail duplication safe).
__global__ __launch_bounds__(256) void gather1(
    const ushort* __restrict__ xw1, const int* __restrict__ offs, const int* __restrict__ ep1,
    const float* __restrict__ bias, const float* __restrict__ g, const float* __restrict__ b,
    ushort* __restrict__ hout)
{
    int n = blockIdx.x * 4 + (threadIdx.x >> 6);
    if (n >= NN) return;
    int lane = threadIdx.x & 63;
    int hf = lane >> 5;               // edge parity handled by this half
    int il = lane & 31;               // col octet 8*il .. 8*il+7
    int cbase = il * 8;
    int e0 = __builtin_amdgcn_readfirstlane(offs[n]);
    int e1 = __builtin_amdgcn_readfirstlane(offs[n + 1]);

    float m[8];
    #pragma unroll
    for (int k = 0; k < 8; k++) m[k] = -INFINITY;

    int e = e0;
    for (; e + 8 <= e1; e += 8) {       // 8 edges: this half takes 4
        int p[4];
        #pragma unroll
        for (int j = 0; j < 4; j++) p[j] = ep1[e + 2 * j + hf];
        uint4 v[4];
        #pragma unroll
        for (int j = 0; j < 4; j++) v[j] = *(const uint4*)&xw1[(size_t)p[j] + cbase];
        #pragma unroll
        for (int j = 0; j < 4; j++) {
            m[0] = fmaxf(m[0], b2f_lo(v[j].x)); m[1] = fmaxf(m[1], b2f_hi(v[j].x));
            m[2] = fmaxf(m[2], b2f_lo(v[j].y)); m[3] = fmaxf(m[3], b2f_hi(v[j].y));
            m[4] = fmaxf(m[4], b2f_lo(v[j].z)); m[5] = fmaxf(m[5], b2f_hi(v[j].z));
            m[6] = fmaxf(m[6], b2f_lo(v[j].w)); m[7] = fmaxf(m[7], b2f_hi(v[j].w));
        }
    }
    for (; e < e1; e += 2) {            // tail: duplicate last edge for odd count (max-safe)
        int ee = min(e + hf, e1 - 1);
        int p = ep1[ee];
        uint4 v = *(const uint4*)&xw1[(size_t)p + cbase];
        m[0] = fmaxf(m[0], b2f_lo(v.x)); m[1] = fmaxf(m[1], b2f_hi(v.x));
        m[2] = fmaxf(m[2], b2f_lo(v.y)); m[3] = fmaxf(m[3], b2f_hi(v.y));
        m[4] = fmaxf(m[4], b2f_lo(v.z)); m[5] = fmaxf(m[5], b2f_hi(v.z));
        m[6] = fmaxf(m[6], b2f_lo(v.w)); m[7] = fmaxf(m[7], b2f_hi(v.w));
    }
    #pragma unroll
    for (int k = 0; k < 8; k++) m[k] = fmaxf(m[k], __shfl_xor(m[k], 32, 64));
    if (e1 == e0) {
        #pragma unroll
        for (int k = 0; k < 8; k++) m[k] = 0.f;
    }

    int c0 = cbase + hf * 4;
    float a0 = hf ? m[4] : m[0];
    float a1 = hf ? m[5] : m[1];
    float a2 = hf ? m[6] : m[2];
    float a3 = hf ? m[7] : m[3];

    ushort4 rt = *(const ushort4*)&xw1[(size_t)n * N1 + NREL * D_HID + c0];
    float t0 = a0 + b2f(rt.x) + bias[c0 + 0];
    float t1 = a1 + b2f(rt.y) + bias[c0 + 1];
    float t2 = a2 + b2f(rt.z) + bias[c0 + 2];
    float t3 = a3 + b2f(rt.w) + bias[c0 + 3];

    float s = t0 + t1 + t2 + t3;
    float s2 = t0 * t0 + t1 * t1 + t2 * t2 + t3 * t3;
    #pragma unroll
    for (int mm = 32; mm >= 1; mm >>= 1) {
        s  += __shfl_xor(s,  mm, 64);
        s2 += __shfl_xor(s2, mm, 64);
    }
    float mu = s * (1.f / D_HID);
    float var = s2 * (1.f / D_HID) - mu * mu;
    float rs = rsqrtf(var + LN_EPS);

    ushort4 o;
    o.x = f2b(fmaxf((t0 - mu) * rs * g[c0 + 0] + b[c0 + 0], 0.f));
    o.y = f2b(fmaxf((t1 - mu) * rs * g[c0 + 1] + b[c0 + 1], 0.f));
    o.z = f2b(fmaxf((t2 - mu) * rs * g[c0 + 2] + b[c0 + 2], 0.f));
    o.w = f2b(fmaxf((t3 - mu) * rs * g[c0 + 3] + b[c0 + 3], 0.f));
    *(ushort4*)&hout[(size_t)n * D_HID + c0] = o;
}

// ---------- gather2: sum over in-edges + root + bias -> LN -> log_softmax -> out ----------
// quarter-wave edge parallelism: 16 lanes x uint2 per edge, 4 edge slots in
// flight; slot sums merged via shfl_xor(16,32); guarded tail.
__global__ __launch_bounds__(256) void gather2(
    const ushort* __restrict__ xw2, const int* __restrict__ offs, const int* __restrict__ ep1,
    const float* __restrict__ bias, const float* __restrict__ g, const float* __restrict__ b,
    float* __restrict__ out)
{
    int n = blockIdx.x * 4 + (threadIdx.x >> 6);
    if (n >= NN) return;
    int lane = threadIdx.x & 63;
    int q = lane >> 4;                // edge slot 0..3
    int ql = lane & 15;               // col quad 4*ql .. 4*ql+3
    int cb = ql * 4;
    int e0 = __builtin_amdgcn_readfirstlane(offs[n]);
    int e1 = __builtin_amdgcn_readfirstlane(offs[n + 1]);

    float s0 = 0.f, s1 = 0.f, s2p = 0.f, s3 = 0.f;
    int e = e0;
    for (; e + 8 <= e1; e += 8) {     // 8 edges: this slot takes e+q, e+4+q
        int pa = ep1[e + q] >> 2;
        int pb = ep1[e + 4 + q] >> 2;
        uint2 va = *(const uint2*)&xw2[(size_t)pa + cb];
        uint2 vb = *(const uint2*)&xw2[(size_t)pb + cb];
        s0 += b2f_lo(va.x) + b2f_lo(vb.x);
        s1 += b2f_hi(va.x) + b2f_hi(vb.x);
        s2p += b2f_lo(va.y) + b2f_lo(vb.y);
        s3 += b2f_hi(va.y) + b2f_hi(vb.y);
    }
    for (; e < e1; e += 4) {
        if (e + q < e1) {
            int p = ep1[e + q] >> 2;
            uint2 v = *(const uint2*)&xw2[(size_t)p + cb];
            s0 += b2f_lo(v.x); s1 += b2f_hi(v.x);
            s2p += b2f_lo(v.y); s3 += b2f_hi(v.y);
        }
    }
    s0 += __shfl_xor(s0, 16, 64); s0 += __shfl_xor(s0, 32, 64);
    s1 += __shfl_xor(s1, 16, 64); s1 += __shfl_xor(s1, 32, 64);
    s2p += __shfl_xor(s2p, 16, 64); s2p += __shfl_xor(s2p, 32, 64);
    s3 += __shfl_xor(s3, 16, 64); s3 += __shfl_xor(s3, 32, 64);

    int c = cb + q;                   // this lane's output column (bijective)
    float agg = (q == 0) ? s0 : (q == 1) ? s1 : (q == 2) ? s2p : s3;
    float v = agg + b2f(xw2[(size_t)n * N2 + NREL * D_OUT + c]) + bias[c];

    float sm = v, sq = v * v;
    #pragma unroll
    for (int mm = 32; mm >= 1; mm >>= 1) {
        sm += __shfl_xor(sm, mm, 64);
        sq += __shfl_xor(sq, mm, 64);
    }
    float mu = sm * (1.f / D_OUT);
    float var = sq * (1.f / D_OUT) - mu * mu;
    float y = (v - mu) * rsqrtf(var + LN_EPS) * g[c] + b[c];

    float mx = y;
    #pragma unroll
    for (int mm = 32; mm >= 1; mm >>= 1) mx = fmaxf(mx, __shfl_xor(mx, mm, 64));
    float ex = __expf(y - mx);
    float se = ex;
    #pragma unroll
    for (int mm = 32; mm >= 1; mm >>= 1) se += __shfl_xor(se, mm, 64);
    out[(size_t)n * D_OUT + c] = y - mx - logf(se);
}

extern "C" void kernel_launch(void* const* d_in, const int* in_sizes, int n_in,
                              void* d_out, int out_size, void* d_ws, size_t ws_size,
                              hipStream_t stream)
{
    const float* x      = (const float*)d_in[0];
    const int*   eidx   = (const int*)  d_in[1];
    const int*   etype  = (const int*)  d_in[2];
    const float* bases1 = (const float*)d_in[3];
    const float* comp1  = (const float*)d_in[4];
    const float* root1  = (const float*)d_in[5];
    const float* bias1  = (const float*)d_in[6];
    const float* g1     = (const float*)d_in[7];
    const float* b1     = (const float*)d_in[8];
    const float* bases2 = (const float*)d_in[9];
    const float* comp2  = (const float*)d_in[10];
    const float* root2  = (const float*)d_in[11];
    const float* bias2  = (const float*)d_in[12];
    const float* g2     = (const float*)d_in[13];
    const float* b2     = (const float*)d_in[14];

    const int* src = eidx;
    const int* dst = eidx + NE;

    char* p = (char*)d_ws;
    auto alloc = [&](size_t bytes) -> char* {
        char* r = p;
        p += (bytes + 255) & ~(size_t)255;
        return r;
    };
    ushort* xbf    = (ushort*)alloc((size_t)NN * D_IN * 2);
    ushort* w1t    = (ushort*)alloc((size_t)N1 * D_IN * 2);
    ushort* w2t    = (ushort*)alloc((size_t)N2 * D_HID * 2);
    ushort* xw1    = (ushort*)alloc((size_t)NN * N1 * 2);
    ushort* xw2    = (ushort*)alloc((size_t)NN * N2 * 2);
    ushort* h      = (ushort*)alloc((size_t)NN * D_HID * 2);
    int*    deg    = (int*)   alloc((size_t)NN * 4);
    int*    local  = (int*)   alloc((size_t)NN * 4);
    int*    bsum   = (int*)   alloc((size_t)NBLK * 4);
    int*    offs   = (int*)   alloc((size_t)(NN + 1) * 4);
    int*    cursor = (int*)   alloc((size_t)NN * 4);
    int*    ep1    = (int*)   alloc((size_t)NE * 4);

    hipMemsetAsync(deg, 0, (size_t)NN * 4, stream);
    const int SZP = D_IN * D_HID + D_HID * D_OUT + NN * D_IN + NE;
    prep_all<<<(SZP + 255) / 256, 256, 0, stream>>>(
        bases1, comp1, root1, bases2, comp2, root2, x, dst, w1t, w2t, xbf, deg);

    scan_blk<<<NBLK, 256, 0, stream>>>(deg, local, bsum);
    scan_fin<<<NBLK, 256, 0, stream>>>(local, bsum, offs, cursor);
    scatter_ep<<<(NE + 255) / 256, 256, 0, stream>>>(src, dst, etype, cursor, ep1);

    gemm_bf16<<<dim3(N1 / 128, (NN + 127) / 128), 512, 0, stream>>>(xbf, w1t, xw1, NN, N1, D_IN);
    gather1<<<(NN + 3) / 4, 256, 0, stream>>>(xw1, offs, ep1, bias1, g1, b1, h);

    gemm_bf16<<<dim3(N2 / 128, (NN + 127) / 128), 512, 0, stream>>>(h, w2t, xw2, NN, N2, D_HID);
    gather2<<<(NN + 3) / 4, 256, 0, stream>>>(xw2, offs, ep1, bias2, g2, b2, (float*)d_out);
}